// Round 5
// baseline (201.610 us; speedup 1.0000x reference)
//
#include <hip/hip_runtime.h>
#include <math.h>

#define BB 8
#define TXT_T 200
#define MEL_T 800
#define N_MEL 80
#define LPT_STRIDE 200   // floats per row of lpT (j dim)
#define LOG2E 1.44269504088896340736f
#define LN2   0.69314718055994530942f
#define EPS2  (1e-7f * LOG2E)      // eps baked into lpT (log2 domain)
#define NPAD  -1.0e12f

__device__ __forceinline__ float exp2_hw(float x) {
#if __has_builtin(__builtin_amdgcn_exp2f)
    return __builtin_amdgcn_exp2f(x);
#else
    return __expf(LN2 * x);
#endif
}

// log2-domain logsumexp: log2(2^A + 2^B). -|d| folds into v_exp input mods.
__device__ __forceinline__ float lse2(float A, float B) {
    float m = fmaxf(A, B);
    float e = exp2_hw(-fabsf(A - B));
    return m + __log2f(1.0f + e);
}

// Kernel 1: lp[b,t,m] = -0.5/80 * ( sum_n (x-mu)^2*exp(-lv) + sum_n lv )
// natural-domain lp -> d_out+1; log2-domain (lp+eps)*log2e -> lpT transposed.
__global__ void __launch_bounds__(256) lp_kernel(
        const float* __restrict__ mu_logvar,   // [B][TXT_T][160]
        const float* __restrict__ melspec,     // [B][N_MEL][MEL_T]
        float* __restrict__ out_lp,            // -> d_out + 1
        float* __restrict__ lpT) {
    const int bt = blockIdx.x;            // b*TXT_T + t
    const int b  = bt / TXT_T;
    const int t  = bt % TXT_T;
    const int tid = threadIdx.x;

    __shared__ float s_mu[N_MEL];
    __shared__ float s_ev[N_MEL];
    __shared__ float s_lv[N_MEL];
    __shared__ float s_sumlv;

    if (tid < N_MEL) {
        float mu = mu_logvar[(size_t)bt * (2 * N_MEL) + tid];
        float lv = mu_logvar[(size_t)bt * (2 * N_MEL) + N_MEL + tid];
        s_mu[tid] = mu;
        s_ev[tid] = __expf(-lv);
        s_lv[tid] = lv;
    }
    __syncthreads();
    if (tid == 0) {
        float s = 0.f;
        #pragma unroll
        for (int n = 0; n < N_MEL; ++n) s += s_lv[n];
        s_sumlv = s;
    }
    __syncthreads();

    if (tid < MEL_T / 4) {
        const float4* ms4 = (const float4*)(melspec + (size_t)b * N_MEL * MEL_T);
        float ax = 0.f, ay = 0.f, az = 0.f, aw = 0.f;
        #pragma unroll 8
        for (int n = 0; n < N_MEL; ++n) {
            float4 x = ms4[(size_t)n * (MEL_T / 4) + tid];
            float mu = s_mu[n];
            float ev = s_ev[n];
            float d0 = x.x - mu; ax += d0 * d0 * ev;
            float d1 = x.y - mu; ay += d1 * d1 * ev;
            float d2 = x.z - mu; az += d2 * d2 * ev;
            float d3 = x.w - mu; aw += d3 * d3 * ev;
        }
        const float c = -0.5f / (float)N_MEL;
        float slv = s_sumlv;
        float l0 = c * (ax + slv);
        float l1 = c * (ay + slv);
        float l2 = c * (az + slv);
        float l3 = c * (aw + slv);

        size_t ob = (size_t)bt * MEL_T + tid * 4;
        out_lp[ob + 0] = l0;
        out_lp[ob + 1] = l1;
        out_lp[ob + 2] = l2;
        out_lp[ob + 3] = l3;

        // transposed, log2-domain with eps baked: lpT[b][m][t]
        int m0 = tid * 4;
        size_t tb = ((size_t)b * MEL_T + m0) * LPT_STRIDE + t;
        lpT[tb + 0 * LPT_STRIDE] = l0 * LOG2E + EPS2;
        lpT[tb + 1 * LPT_STRIDE] = l1 * LOG2E + EPS2;
        lpT[tb + 2 * LPT_STRIDE] = l2 * LOG2E + EPS2;
        lpT[tb + 3 * LPT_STRIDE] = l3 * LOG2E + EPS2;
    }
}

#define PF 8
#define LD(row)  (*(const float4*)(base + (size_t)(row) * LPT_STRIDE))
#define LD2(row) (*(const float4*)(base + (size_t)(row) * LPT_STRIDE + 4))

// one step: consume (AK,BK) = lp rows for this lane's 8 j's at time TT,
// prefetch row TT+PF, advance recurrence. All names static -> registers.
#define STEP(AK, BK, TT) do {                                                 \
    float4 lpA_ = AK; float4 lpB_ = BK;                                       \
    int row_ = (TT) + PF;                                                     \
    row_ = row_ > (MEL_T - 1) ? (MEL_T - 1) : row_;                           \
    AK = LD(row_); BK = LD2(row_);                                            \
    float left_ = __shfl_up(r7, 1);                                           \
    if (li == 0) left_ = NPAD;   /* batch-local j=0 left pad (lanes 0,32) */  \
    float n0_ = lse2(r0, left_) + lpA_.x;                                     \
    float n1_ = lse2(r1, r0)    + lpA_.y;                                     \
    float n2_ = lse2(r2, r1)    + lpA_.z;                                     \
    float n3_ = lse2(r3, r2)    + lpA_.w;                                     \
    float n4_ = lse2(r4, r3)    + lpB_.x;                                     \
    float n5_ = lse2(r5, r4)    + lpB_.y;                                     \
    float n6_ = lse2(r6, r5)    + lpB_.z;                                     \
    float n7_ = lse2(r7, r6)    + lpB_.w;                                     \
    r0=n0_; r1=n1_; r2=n2_; r3=n3_; r4=n4_; r5=n5_; r6=n6_; r7=n7_;           \
    if ((TT) == myMel) {   /* rare divergent branch: body runs ~2x total */   \
        float v_ = r0;                                                        \
        if (acomp == 1) v_ = r1;                                              \
        if (acomp == 2) v_ = r2;                                              \
        if (acomp == 3) v_ = r3;                                              \
        if (acomp == 4) v_ = r4;                                              \
        if (acomp == 5) v_ = r5;                                              \
        if (acomp == 6) v_ = r6;                                              \
        if (acomp == 7) v_ = r7;                                              \
        alpha_out[batch] = v_ * scale;                                        \
    }                                                                         \
} while (0)

// Kernel 2: 2 independent batch scans per wave (lanes 0-24 / 32-56), 8 j/lane.
// Doubles the ILP filling dependency stalls of the serial recurrence.
__global__ void __launch_bounds__(64) scan_kernel(
        const float* __restrict__ lpT,          // [B][MEL_T][LPT_STRIDE], log2-domain
        const int* __restrict__ text_lengths,
        const int* __restrict__ mel_lengths,
        float* __restrict__ alpha_out) {        // [B], natural-domain alpha/mel_len
    const int lane = threadIdx.x;
    const int half = lane >> 5;
    const int li   = lane & 31;
    const int batch = blockIdx.x * 2 + half;
    int jl = li * 8;
    jl = jl > (TXT_T - 8) ? (TXT_T - 8) : jl;   // clamp idle lanes 25..31

    const int melL1 = mel_lengths[batch] - 1;   // >= 399
    const int txtL1 = text_lengths[batch] - 1;  // 99..199 -> alane 12..24
    const float scale = LN2 / (float)(melL1 + 1);  // back to natural + /mel_len
    const int acomp = txtL1 & 7;
    const int myMel = (li == (txtL1 >> 3)) ? melL1 : -1;

    const float* base = lpT + (size_t)batch * MEL_T * LPT_STRIDE + jl;

    // init state after t=0: a[0] = lp(0,0) (no eps), rest -inf
    float4 i0 = LD(0);
    float r0 = (li == 0) ? (i0.x - EPS2) : NPAD;
    float r1 = NPAD, r2 = NPAD, r3 = NPAD, r4 = NPAD, r5 = NPAD, r6 = NPAD, r7 = NPAD;

    // prefetch ring: rows 1..8, 2 float4 per lane per row
    float4 a0 = LD(1), b0 = LD2(1);
    float4 a1 = LD(2), b1 = LD2(2);
    float4 a2 = LD(3), b2 = LD2(3);
    float4 a3 = LD(4), b3 = LD2(4);
    float4 a4 = LD(5), b4 = LD2(5);
    float4 a5 = LD(6), b5 = LD2(6);
    float4 a6 = LD(7), b6 = LD2(7);
    float4 a7 = LD(8), b7 = LD2(8);

    for (int t = 1; t < MEL_T; t += PF) {   // t = 1,9,...,793 -> 100 chunks
        STEP(a0, b0, t + 0);
        STEP(a1, b1, t + 1);
        STEP(a2, b2, t + 2);
        STEP(a3, b3, t + 3);
        STEP(a4, b4, t + 4);
        STEP(a5, b5, t + 5);
        STEP(a6, b6, t + 6);
        STEP(a7, b7, t + 7);   // tt=800 overrun harmless (myMel<=799)
    }
}

// Kernel 3: loss = -mean_b alpha[b]
__global__ void finish_kernel(const float* __restrict__ alpha,
                              float* __restrict__ out) {
    float s = 0.f;
    #pragma unroll
    for (int b = 0; b < BB; ++b) s += alpha[b];
    out[0] = -(s / (float)BB);
}

extern "C" void kernel_launch(void* const* d_in, const int* in_sizes, int n_in,
                              void* d_out, int out_size, void* d_ws, size_t ws_size,
                              hipStream_t stream) {
    const float* mu_logvar    = (const float*)d_in[0];
    const float* melspec      = (const float*)d_in[1];
    const int*   text_lengths = (const int*)d_in[2];
    const int*   mel_lengths  = (const int*)d_in[3];
    float* out = (float*)d_out;

    float* alpha = (float*)d_ws;                 // 8 floats
    float* lpT   = (float*)d_ws + 16;            // 64B offset, [B][MEL_T][LPT_STRIDE]

    lp_kernel<<<BB * TXT_T, 256, 0, stream>>>(mu_logvar, melspec, out + 1, lpT);
    scan_kernel<<<BB / 2, 64, 0, stream>>>(lpT, text_lengths, mel_lengths, alpha);
    finish_kernel<<<1, 1, 0, stream>>>(alpha, out);
}

// Round 6
// 156.769 us; speedup vs baseline: 1.2860x; 1.2860x over previous
//
#include <hip/hip_runtime.h>
#include <math.h>

#define BB 8
#define TXT_T 200
#define MEL_T 800
#define N_MEL 80
#define LPT_STRIDE 200   // floats per row of lpT (j dim)
#define LOG2E 1.44269504088896340736f
#define LN2   0.69314718055994530942f
#define EPS2  (1e-7f * LOG2E)      // eps baked into lpT (log2 domain)
#define NPAD  -1.0e12f

__device__ __forceinline__ float exp2_hw(float x) {
#if __has_builtin(__builtin_amdgcn_exp2f)
    return __builtin_amdgcn_exp2f(x);
#else
    return __expf(LN2 * x);
#endif
}

// log2-domain logsumexp2: log2(2^A + 2^B)
__device__ __forceinline__ float lse2(float A, float B) {
    float m = fmaxf(A, B);
    float e = exp2_hw(-fabsf(A - B));
    return m + __log2f(1.0f + e);
}

// log2-domain logsumexp3: log2(2^A + 2^B + 2^C)
__device__ __forceinline__ float lse3(float A, float B, float C) {
    float m = fmaxf(fmaxf(A, B), C);     // v_max3
    float e = exp2_hw(A - m) + exp2_hw(B - m) + exp2_hw(C - m);
    return m + __log2f(e);
}

// Kernel 1: lp[b,t,m] = -0.5/80 * ( sum_n (x-mu)^2*exp(-lv) + sum_n lv )
// natural-domain lp -> d_out+1; log2-domain (lp*log2e + eps2) -> lpT transposed.
__global__ void __launch_bounds__(256) lp_kernel(
        const float* __restrict__ mu_logvar,   // [B][TXT_T][160]
        const float* __restrict__ melspec,     // [B][N_MEL][MEL_T]
        float* __restrict__ out_lp,            // -> d_out + 1
        float* __restrict__ lpT) {
    const int bt = blockIdx.x;            // b*TXT_T + t
    const int b  = bt / TXT_T;
    const int t  = bt % TXT_T;
    const int tid = threadIdx.x;

    __shared__ float s_mu[N_MEL];
    __shared__ float s_ev[N_MEL];
    __shared__ float s_lv[N_MEL];
    __shared__ float s_sumlv;

    if (tid < N_MEL) {
        float mu = mu_logvar[(size_t)bt * (2 * N_MEL) + tid];
        float lv = mu_logvar[(size_t)bt * (2 * N_MEL) + N_MEL + tid];
        s_mu[tid] = mu;
        s_ev[tid] = __expf(-lv);
        s_lv[tid] = lv;
    }
    __syncthreads();
    if (tid == 0) {
        float s = 0.f;
        #pragma unroll
        for (int n = 0; n < N_MEL; ++n) s += s_lv[n];
        s_sumlv = s;
    }
    __syncthreads();

    if (tid < MEL_T / 4) {
        const float4* ms4 = (const float4*)(melspec + (size_t)b * N_MEL * MEL_T);
        float ax = 0.f, ay = 0.f, az = 0.f, aw = 0.f;
        #pragma unroll 8
        for (int n = 0; n < N_MEL; ++n) {
            float4 x = ms4[(size_t)n * (MEL_T / 4) + tid];
            float mu = s_mu[n];
            float ev = s_ev[n];
            float d0 = x.x - mu; ax += d0 * d0 * ev;
            float d1 = x.y - mu; ay += d1 * d1 * ev;
            float d2 = x.z - mu; az += d2 * d2 * ev;
            float d3 = x.w - mu; aw += d3 * d3 * ev;
        }
        const float c = -0.5f / (float)N_MEL;
        float slv = s_sumlv;
        float l0 = c * (ax + slv);
        float l1 = c * (ay + slv);
        float l2 = c * (az + slv);
        float l3 = c * (aw + slv);

        size_t ob = (size_t)bt * MEL_T + tid * 4;
        out_lp[ob + 0] = l0;
        out_lp[ob + 1] = l1;
        out_lp[ob + 2] = l2;
        out_lp[ob + 3] = l3;

        // transposed, log2-domain with eps baked: lpT[b][m][t]
        int m0 = tid * 4;
        size_t tb = ((size_t)b * MEL_T + m0) * LPT_STRIDE + t;
        lpT[tb + 0 * LPT_STRIDE] = l0 * LOG2E + EPS2;
        lpT[tb + 1 * LPT_STRIDE] = l1 * LOG2E + EPS2;
        lpT[tb + 2 * LPT_STRIDE] = l2 * LOG2E + EPS2;
        lpT[tb + 3 * LPT_STRIDE] = l3 * LOG2E + EPS2;
    }
}

#define PF 8    // pairs (2 mel steps each) in flight
#define LDR(row) (*(const float4*)(base + (size_t)(row) * LPT_STRIDE))

// Two composed mel steps (TT, TT+1):
//   r''_j = lse3(r_j + p_j, r_{j-1} + s_j, r_{j-2} + p_{j-1}) + q_j
//   s_j = lse2(p_j, p_{j-1})  -- off the critical chain (p prefetched early)
// The intermediate state r(TT) is only materialized inside the rare gather
// branch. All names static -> registers.
#define STEP2(PK, QK, TT) do {                                                \
    float4 p_ = PK; float4 q_ = QK;                                           \
    int rp_ = (TT) + 2 * PF;                                                  \
    int ra_ = rp_     > (MEL_T - 1) ? (MEL_T - 1) : rp_;                      \
    int rb_ = rp_ + 1 > (MEL_T - 1) ? (MEL_T - 1) : rp_ + 1;                  \
    PK = LDR(ra_); QK = LDR(rb_);                                             \
    float l1_ = __shfl_up(r3, 1);                                             \
    float l2_ = __shfl_up(r2, 1);                                             \
    float pw_ = __shfl_up(p_.w, 1);                                           \
    if (lane == 0) { l1_ = NPAD; l2_ = NPAD; pw_ = NPAD; }                    \
    if ((TT) == myMel) {   /* rare: mel end on the intermediate step */       \
        float ga_ = r0, gb_ = l1_, gp_ = p_.x;                                \
        if (acomp == 1) { ga_ = r1; gb_ = r0; gp_ = p_.y; }                   \
        if (acomp == 2) { ga_ = r2; gb_ = r1; gp_ = p_.z; }                   \
        if (acomp == 3) { ga_ = r3; gb_ = r2; gp_ = p_.w; }                   \
        alpha_out[b] = (lse2(ga_, gb_) + gp_) * scale;                        \
    }                                                                         \
    float s0_ = lse2(p_.x, pw_);                                              \
    float s1_ = lse2(p_.y, p_.x);                                             \
    float s2_ = lse2(p_.z, p_.y);                                             \
    float s3_ = lse2(p_.w, p_.z);                                             \
    float x0_ = r0 + p_.x, x1_ = r1 + p_.y, x2_ = r2 + p_.z, x3_ = r3 + p_.w; \
    float y0_ = l1_ + s0_, y1_ = r0 + s1_, y2_ = r1 + s2_, y3_ = r2 + s3_;    \
    float z0_ = l2_ + pw_, z1_ = l1_ + p_.x, z2_ = r0 + p_.y, z3_ = r1 + p_.z;\
    r0 = lse3(x0_, y0_, z0_) + q_.x;                                          \
    r1 = lse3(x1_, y1_, z1_) + q_.y;                                          \
    r2 = lse3(x2_, y2_, z2_) + q_.z;                                          \
    r3 = lse3(x3_, y3_, z3_) + q_.w;                                          \
    if ((TT) + 1 == myMel) {   /* rare: mel end on the composed step */       \
        float v_ = r0;                                                        \
        if (acomp == 1) v_ = r1;                                              \
        if (acomp == 2) v_ = r2;                                              \
        if (acomp == 3) v_ = r3;                                              \
        alpha_out[b] = v_ * scale;                                            \
    }                                                                         \
} while (0)

// Kernel 2: serial scan, one wave per batch, 4 j per lane (lanes 0..49),
// two mel steps composed per update; early exit at this batch's mel length.
__global__ void __launch_bounds__(64) scan_kernel(
        const float* __restrict__ lpT,          // [B][MEL_T][LPT_STRIDE], log2-dom
        const int* __restrict__ text_lengths,
        const int* __restrict__ mel_lengths,
        float* __restrict__ alpha_out) {        // [B]
    const int b = blockIdx.x;
    const int lane = threadIdx.x;
    int j0 = lane * 4;
    j0 = j0 > (TXT_T - 4) ? (TXT_T - 4) : j0;   // clamp idle lanes 50..63

    const int melL1 = mel_lengths[b] - 1;       // >= 399
    const int txtL1 = text_lengths[b] - 1;      // 99..199
    const float scale = LN2 / (float)(melL1 + 1);
    const int acomp = txtL1 & 3;
    const int myMel = (lane == (txtL1 >> 2)) ? melL1 : -1;

    const float* base = lpT + (size_t)b * MEL_T * LPT_STRIDE + j0;

    // state after t=0: a[j=0] = lp(0,0) (no eps), rest -inf  (log2 domain)
    float4 i0 = LDR(0);
    float r0 = (lane == 0) ? (i0.x - EPS2) : NPAD;
    float r1 = NPAD, r2 = NPAD, r3 = NPAD;

    // prefetch ring: PF pairs = rows 1..2*PF
    float4 P0 = LDR(1),  Q0 = LDR(2);
    float4 P1 = LDR(3),  Q1 = LDR(4);
    float4 P2 = LDR(5),  Q2 = LDR(6);
    float4 P3 = LDR(7),  Q3 = LDR(8);
    float4 P4 = LDR(9),  Q4 = LDR(10);
    float4 P5 = LDR(11), Q5 = LDR(12);
    float4 P6 = LDR(13), Q6 = LDR(14);
    float4 P7 = LDR(15), Q7 = LDR(16);

    // chunks of PF pairs; stop once this batch's mel end has been passed.
    for (int t = 1; t <= melL1; t += 2 * PF) {
        STEP2(P0, Q0, t + 0);
        STEP2(P1, Q1, t + 2);
        STEP2(P2, Q2, t + 4);
        STEP2(P3, Q3, t + 6);
        STEP2(P4, Q4, t + 8);
        STEP2(P5, Q5, t + 10);
        STEP2(P6, Q6, t + 12);
        STEP2(P7, Q7, t + 14);   // overrun past melL1 harmless (rows clamped)
    }
}

// Kernel 3: loss = -mean_b alpha[b]
__global__ void finish_kernel(const float* __restrict__ alpha,
                              float* __restrict__ out) {
    float s = 0.f;
    #pragma unroll
    for (int b = 0; b < BB; ++b) s += alpha[b];
    out[0] = -(s / (float)BB);
}

extern "C" void kernel_launch(void* const* d_in, const int* in_sizes, int n_in,
                              void* d_out, int out_size, void* d_ws, size_t ws_size,
                              hipStream_t stream) {
    const float* mu_logvar    = (const float*)d_in[0];
    const float* melspec      = (const float*)d_in[1];
    const int*   text_lengths = (const int*)d_in[2];
    const int*   mel_lengths  = (const int*)d_in[3];
    float* out = (float*)d_out;

    float* alpha = (float*)d_ws;                 // 8 floats
    float* lpT   = (float*)d_ws + 16;            // 64B offset, [B][MEL_T][LPT_STRIDE]

    lp_kernel<<<BB * TXT_T, 256, 0, stream>>>(mu_logvar, melspec, out + 1, lpT);
    scan_kernel<<<BB, 64, 0, stream>>>(lpT, text_lengths, mel_lengths, alpha);
    finish_kernel<<<1, 1, 0, stream>>>(alpha, out);
}

// Round 7
// 156.143 us; speedup vs baseline: 1.2912x; 1.0040x over previous
//
#include <hip/hip_runtime.h>
#include <math.h>

#define BB 8
#define TXT_T 200
#define MEL_T 800
#define N_MEL 80
#define LPT_STRIDE 200   // floats per row of lpT (j dim)
#define CH 32            // mel rows per staged chunk (32*800B = 25600B = 25 insts)
#define LOG2E 1.44269504088896340736f
#define LN2   0.69314718055994530942f
#define EPS2  (1e-7f * LOG2E)      // eps baked into lpT (log2 domain)
#define NPAD  -1.0e12f

__device__ __forceinline__ float exp2_hw(float x) {
#if __has_builtin(__builtin_amdgcn_exp2f)
    return __builtin_amdgcn_exp2f(x);
#else
    return __expf(LN2 * x);
#endif
}

// log2-domain logsumexp2: log2(2^A + 2^B)
__device__ __forceinline__ float lse2(float A, float B) {
    float m = fmaxf(A, B);
    float e = exp2_hw(-fabsf(A - B));
    return m + __log2f(1.0f + e);
}

// log2-domain logsumexp3: log2(2^A + 2^B + 2^C)
__device__ __forceinline__ float lse3(float A, float B, float C) {
    float m = fmaxf(fmaxf(A, B), C);     // v_max3
    float e = exp2_hw(A - m) + exp2_hw(B - m) + exp2_hw(C - m);
    return m + __log2f(e);
}

// Kernel 1: lp[b,t,m] = -0.5/80 * ( sum_n (x-mu)^2*exp(-lv) + sum_n lv )
// natural-domain lp -> d_out+1; log2-domain (lp*log2e + eps2) -> lpT transposed.
__global__ void __launch_bounds__(256) lp_kernel(
        const float* __restrict__ mu_logvar,   // [B][TXT_T][160]
        const float* __restrict__ melspec,     // [B][N_MEL][MEL_T]
        float* __restrict__ out_lp,            // -> d_out + 1
        float* __restrict__ lpT) {
    const int bt = blockIdx.x;            // b*TXT_T + t
    const int b  = bt / TXT_T;
    const int t  = bt % TXT_T;
    const int tid = threadIdx.x;

    __shared__ float s_mu[N_MEL];
    __shared__ float s_ev[N_MEL];
    __shared__ float s_lv[N_MEL];
    __shared__ float s_sumlv;

    if (tid < N_MEL) {
        float mu = mu_logvar[(size_t)bt * (2 * N_MEL) + tid];
        float lv = mu_logvar[(size_t)bt * (2 * N_MEL) + N_MEL + tid];
        s_mu[tid] = mu;
        s_ev[tid] = __expf(-lv);
        s_lv[tid] = lv;
    }
    __syncthreads();
    if (tid == 0) {
        float s = 0.f;
        #pragma unroll
        for (int n = 0; n < N_MEL; ++n) s += s_lv[n];
        s_sumlv = s;
    }
    __syncthreads();

    if (tid < MEL_T / 4) {
        const float4* ms4 = (const float4*)(melspec + (size_t)b * N_MEL * MEL_T);
        float ax = 0.f, ay = 0.f, az = 0.f, aw = 0.f;
        #pragma unroll 8
        for (int n = 0; n < N_MEL; ++n) {
            float4 x = ms4[(size_t)n * (MEL_T / 4) + tid];
            float mu = s_mu[n];
            float ev = s_ev[n];
            float d0 = x.x - mu; ax += d0 * d0 * ev;
            float d1 = x.y - mu; ay += d1 * d1 * ev;
            float d2 = x.z - mu; az += d2 * d2 * ev;
            float d3 = x.w - mu; aw += d3 * d3 * ev;
        }
        const float c = -0.5f / (float)N_MEL;
        float slv = s_sumlv;
        float l0 = c * (ax + slv);
        float l1 = c * (ay + slv);
        float l2 = c * (az + slv);
        float l3 = c * (aw + slv);

        size_t ob = (size_t)bt * MEL_T + tid * 4;
        out_lp[ob + 0] = l0;
        out_lp[ob + 1] = l1;
        out_lp[ob + 2] = l2;
        out_lp[ob + 3] = l3;

        // transposed, log2-domain with eps baked: lpT[b][m][t]
        int m0 = tid * 4;
        size_t tb = ((size_t)b * MEL_T + m0) * LPT_STRIDE + t;
        lpT[tb + 0 * LPT_STRIDE] = l0 * LOG2E + EPS2;
        lpT[tb + 1 * LPT_STRIDE] = l1 * LOG2E + EPS2;
        lpT[tb + 2 * LPT_STRIDE] = l2 * LOG2E + EPS2;
        lpT[tb + 3 * LPT_STRIDE] = l3 * LOG2E + EPS2;
    }
}

// async-stage one 32-row chunk (25600 B) global -> LDS; 25 x 1024B insts.
// LDS dest is wave-uniform base + lane*16 (HW); global src per-lane.
__device__ __forceinline__ void stage_chunk(const float* g, float* s, int lane) {
    #pragma unroll
    for (int i = 0; i < 25; ++i) {
        __builtin_amdgcn_global_load_lds(
            (const __attribute__((address_space(1))) void*)(g + i * 256 + lane * 4),
            (__attribute__((address_space(3))) void*)(s + i * 256),
            16, 0, 0);
    }
}

// Two composed mel steps (TT, TT+1), lp rows read from LDS at TLOC, TLOC+1:
//   r''_j = lse3(r_j + p_j, r_{j-1} + s_j, r_{j-2} + p_{j-1}) + q_j
//   s_j = lse2(p_j, p_{j-1})  -- off the carried chain
#define STEP2L(SB, TLOC, TT) do {                                             \
    float4 p_ = *(const float4*)((SB) + (TLOC) * LPT_STRIDE + j0);            \
    float4 q_ = *(const float4*)((SB) + ((TLOC) + 1) * LPT_STRIDE + j0);      \
    float l1_ = __shfl_up(r3, 1);                                             \
    float l2_ = __shfl_up(r2, 1);                                             \
    float pw_ = __shfl_up(p_.w, 1);                                           \
    if (lane == 0) { l1_ = NPAD; l2_ = NPAD; pw_ = NPAD; }                    \
    if ((TT) == myMel) {   /* rare: mel end on the intermediate step */       \
        float ga_ = r0, gb_ = l1_, gp_ = p_.x;                                \
        if (acomp == 1) { ga_ = r1; gb_ = r0; gp_ = p_.y; }                   \
        if (acomp == 2) { ga_ = r2; gb_ = r1; gp_ = p_.z; }                   \
        if (acomp == 3) { ga_ = r3; gb_ = r2; gp_ = p_.w; }                   \
        alpha_out[b] = (lse2(ga_, gb_) + gp_) * scale;                        \
    }                                                                         \
    float s0_ = lse2(p_.x, pw_);                                              \
    float s1_ = lse2(p_.y, p_.x);                                             \
    float s2_ = lse2(p_.z, p_.y);                                             \
    float s3_ = lse2(p_.w, p_.z);                                             \
    float x0_ = r0 + p_.x, x1_ = r1 + p_.y, x2_ = r2 + p_.z, x3_ = r3 + p_.w; \
    float y0_ = l1_ + s0_, y1_ = r0 + s1_, y2_ = r1 + s2_, y3_ = r2 + s3_;    \
    float z0_ = l2_ + pw_, z1_ = l1_ + p_.x, z2_ = r0 + p_.y, z3_ = r1 + p_.z;\
    r0 = lse3(x0_, y0_, z0_) + q_.x;                                          \
    r1 = lse3(x1_, y1_, z1_) + q_.y;                                          \
    r2 = lse3(x2_, y2_, z2_) + q_.z;                                          \
    r3 = lse3(x3_, y3_, z3_) + q_.w;                                          \
    if ((TT) + 1 == myMel) {   /* rare: mel end on the composed step */       \
        float v_ = r0;                                                        \
        if (acomp == 1) v_ = r1;                                              \
        if (acomp == 2) v_ = r2;                                              \
        if (acomp == 3) v_ = r3;                                              \
        alpha_out[b] = v_ * scale;                                            \
    }                                                                         \
} while (0)

// Kernel 2: serial scan, one wave per batch. lp rows staged 32 at a time into
// double-buffered LDS via async global_load_lds (counted vmcnt, never drain
// mid-pipeline); compute reads ds_read_b128. Pairs aligned to chunks:
// chunk 0 = init + single step t=1 + pairs (2,3)..(30,31); chunk c>=1 =
// pairs (32c,32c+1)..(32c+30,32c+31).
__global__ void __launch_bounds__(64) scan_kernel(
        const float* __restrict__ lpT,          // [B][MEL_T][LPT_STRIDE], log2-dom
        const int* __restrict__ text_lengths,
        const int* __restrict__ mel_lengths,
        float* __restrict__ alpha_out) {        // [B]
    __shared__ float sbuf[2][CH][LPT_STRIDE];   // 51200 B
    const int b = blockIdx.x;
    const int lane = threadIdx.x;
    int j0 = lane * 4;
    j0 = j0 > (TXT_T - 4) ? (TXT_T - 4) : j0;   // clamp idle lanes 50..63

    const int melL1 = mel_lengths[b] - 1;       // in [399, 799]
    const int txtL1 = text_lengths[b] - 1;      // in [99, 199]
    const float scale = LN2 / (float)(melL1 + 1);
    const int acomp = txtL1 & 3;
    const int myMel = (lane == (txtL1 >> 2)) ? melL1 : -1;

    const float* gbase = lpT + (size_t)b * MEL_T * LPT_STRIDE;
    const int clast = melL1 >> 5;               // in [12, 24]

    stage_chunk(gbase,                    &sbuf[0][0][0], lane);
    stage_chunk(gbase + CH * LPT_STRIDE,  &sbuf[1][0][0], lane);

    float r0 = NPAD, r1 = NPAD, r2 = NPAD, r3 = NPAD;

    for (int c = 0; c <= clast; ++c) {
        // chunk c ready; chunk c+1 (if staged) may stay in flight
        if (c < clast) { asm volatile("s_waitcnt vmcnt(25)" ::: "memory"); }
        else           { asm volatile("s_waitcnt vmcnt(0)"  ::: "memory"); }

        const float* sb = &sbuf[c & 1][0][0];
        if (c == 0) {
            float4 row0 = *(const float4*)(sb + j0);
            float4 row1 = *(const float4*)(sb + LPT_STRIDE + j0);
            // state after t=0: a[j=0] = lp(0,0) (no eps), rest -inf
            r0 = (lane == 0) ? (row0.x - EPS2) : NPAD;
            // single step t=1 (melL1 >= 399, no gather possible here)
            float lft = __shfl_up(r3, 1);
            if (lane == 0) lft = NPAD;
            float m0 = lse2(r0, lft) + row1.x;
            float m1 = lse2(r1, r0)  + row1.y;
            float m2 = lse2(r2, r1)  + row1.z;
            float m3 = lse2(r3, r2)  + row1.w;
            r0 = m0; r1 = m1; r2 = m2; r3 = m3;
            #pragma unroll
            for (int m = 0; m < 15; ++m) {
                STEP2L(sb, 2 * m + 2, 2 * m + 2);
            }
        } else {
            const int tbase = 32 * c;
            #pragma unroll
            for (int m = 0; m < 16; ++m) {
                STEP2L(sb, 2 * m, tbase + 2 * m);
            }
        }

        if (c + 2 <= clast) {
            stage_chunk(gbase + (size_t)(c + 2) * CH * LPT_STRIDE,
                        &sbuf[c & 1][0][0], lane);
        }
    }
}

// Kernel 3: loss = -mean_b alpha[b]
__global__ void finish_kernel(const float* __restrict__ alpha,
                              float* __restrict__ out) {
    float s = 0.f;
    #pragma unroll
    for (int b = 0; b < BB; ++b) s += alpha[b];
    out[0] = -(s / (float)BB);
}

extern "C" void kernel_launch(void* const* d_in, const int* in_sizes, int n_in,
                              void* d_out, int out_size, void* d_ws, size_t ws_size,
                              hipStream_t stream) {
    const float* mu_logvar    = (const float*)d_in[0];
    const float* melspec      = (const float*)d_in[1];
    const int*   text_lengths = (const int*)d_in[2];
    const int*   mel_lengths  = (const int*)d_in[3];
    float* out = (float*)d_out;

    float* alpha = (float*)d_ws;                 // 8 floats
    float* lpT   = (float*)d_ws + 16;            // 64B offset, [B][MEL_T][LPT_STRIDE]

    lp_kernel<<<BB * TXT_T, 256, 0, stream>>>(mu_logvar, melspec, out + 1, lpT);
    scan_kernel<<<BB, 64, 0, stream>>>(lpT, text_lengths, mel_lengths, alpha);
    finish_kernel<<<1, 1, 0, stream>>>(alpha, out);
}

// Round 8
// 126.548 us; speedup vs baseline: 1.5931x; 1.2339x over previous
//
#include <hip/hip_runtime.h>
#include <math.h>

#define BB 8
#define TXT_T 200
#define MEL_T 800
#define N_MEL 80
#define GSTR 256         // padded floats per lpT row (1024 B = 1 global_load_lds)
#define CH 16            // mel rows per staged chunk (16 KiB; 4 insts per wave)
#define LOG2E 1.44269504088896340736f
#define LN2   0.69314718055994530942f
#define EPS2  (1e-7f * LOG2E)      // eps baked into lpT (log2 domain)
#define NPAD  -1.0e12f

#define SBAR()       asm volatile("s_barrier" ::: "memory")
#define WAIT_LGKM0() asm volatile("s_waitcnt lgkmcnt(0)" ::: "memory")

__device__ __forceinline__ float exp2_hw(float x) {
#if __has_builtin(__builtin_amdgcn_exp2f)
    return __builtin_amdgcn_exp2f(x);
#else
    return __expf(LN2 * x);
#endif
}

// log2-domain logsumexp2: log2(2^A + 2^B)
__device__ __forceinline__ float lse2(float A, float B) {
    float m = fmaxf(A, B);
    float e = exp2_hw(-fabsf(A - B));
    return m + __log2f(1.0f + e);
}

// log2-domain logsumexp3: log2(2^A + 2^B + 2^C)
__device__ __forceinline__ float lse3(float A, float B, float C) {
    float m = fmaxf(fmaxf(A, B), C);     // v_max3
    float e = exp2_hw(A - m) + exp2_hw(B - m) + exp2_hw(C - m);
    return m + __log2f(e);
}

// Kernel 1: lp[b,t,m] = -0.5/80 * ( sum_n (x-mu)^2*exp(-lv) + sum_n lv )
// natural-domain lp -> d_out+1; log2-domain (lp*log2e + eps2) -> lpT
// transposed [b][m][j] with row stride GSTR (pad uninitialized, never read).
__global__ void __launch_bounds__(256) lp_kernel(
        const float* __restrict__ mu_logvar,   // [B][TXT_T][160]
        const float* __restrict__ melspec,     // [B][N_MEL][MEL_T]
        float* __restrict__ out_lp,            // -> d_out + 1
        float* __restrict__ lpT) {
    const int bt = blockIdx.x;            // b*TXT_T + t
    const int b  = bt / TXT_T;
    const int t  = bt % TXT_T;
    const int tid = threadIdx.x;

    __shared__ float s_mu[N_MEL];
    __shared__ float s_ev[N_MEL];
    __shared__ float s_lv[N_MEL];
    __shared__ float s_sumlv;

    if (tid < N_MEL) {
        float mu = mu_logvar[(size_t)bt * (2 * N_MEL) + tid];
        float lv = mu_logvar[(size_t)bt * (2 * N_MEL) + N_MEL + tid];
        s_mu[tid] = mu;
        s_ev[tid] = __expf(-lv);
        s_lv[tid] = lv;
    }
    __syncthreads();
    if (tid == 0) {
        float s = 0.f;
        #pragma unroll
        for (int n = 0; n < N_MEL; ++n) s += s_lv[n];
        s_sumlv = s;
    }
    __syncthreads();

    if (tid < MEL_T / 4) {
        const float4* ms4 = (const float4*)(melspec + (size_t)b * N_MEL * MEL_T);
        float ax = 0.f, ay = 0.f, az = 0.f, aw = 0.f;
        #pragma unroll 8
        for (int n = 0; n < N_MEL; ++n) {
            float4 x = ms4[(size_t)n * (MEL_T / 4) + tid];
            float mu = s_mu[n];
            float ev = s_ev[n];
            float d0 = x.x - mu; ax += d0 * d0 * ev;
            float d1 = x.y - mu; ay += d1 * d1 * ev;
            float d2 = x.z - mu; az += d2 * d2 * ev;
            float d3 = x.w - mu; aw += d3 * d3 * ev;
        }
        const float c = -0.5f / (float)N_MEL;
        float slv = s_sumlv;
        float l0 = c * (ax + slv);
        float l1 = c * (ay + slv);
        float l2 = c * (az + slv);
        float l3 = c * (aw + slv);

        size_t ob = (size_t)bt * MEL_T + tid * 4;
        out_lp[ob + 0] = l0;
        out_lp[ob + 1] = l1;
        out_lp[ob + 2] = l2;
        out_lp[ob + 3] = l3;

        // transposed, log2-domain with eps baked: lpT[b][m][t], stride GSTR
        int m0 = tid * 4;
        size_t tb = ((size_t)(b * MEL_T + m0)) * GSTR + t;
        lpT[tb + 0 * GSTR] = l0 * LOG2E + EPS2;
        lpT[tb + 1 * GSTR] = l1 * LOG2E + EPS2;
        lpT[tb + 2 * GSTR] = l2 * LOG2E + EPS2;
        lpT[tb + 3 * GSTR] = l3 * LOG2E + EPS2;
    }
}

// async-stage one 16-row chunk (16 KiB) global -> LDS, split across 4 waves:
// wave w stages rows 4w..4w+3, one 1024B inst per row -> 4 insts per wave.
__device__ __forceinline__ void stage16(const float* g, float* s, int w, int lane) {
    #pragma unroll
    for (int k = 0; k < 4; ++k) {
        int row = w * 4 + k;
        __builtin_amdgcn_global_load_lds(
            (const __attribute__((address_space(1))) void*)(g + row * GSTR + lane * 4),
            (__attribute__((address_space(3))) void*)(s + row * GSTR),
            16, 0, 0);
    }
}

// Two composed mel steps (TT, TT+1), one j per thread:
//   r' = lse3(r + p, r_{j-1} + lse2(p, p_{j-1}), r_{j-2} + p_{j-1}) + q
// Cross-thread r_{j-1}, r_{j-2} via parity-dbuf LDS rbuf + raw s_barrier.
// p/pm/q issued before the barrier to hide LDS latency under the exchange.
#define PAIRL(SB, TLOC, TT) do {                                              \
    float* rb_ = &rbuf[par][0];                                               \
    float p_  = (SB)[(TLOC) * GSTR + j];                                      \
    float pm_ = (SB)[(TLOC) * GSTR + jm1];                                    \
    float q_  = (SB)[((TLOC) + 1) * GSTR + j];                                \
    rb_[tid] = r;                                                             \
    WAIT_LGKM0(); SBAR();                                                     \
    float rm1_ = rb_[tm1];                                                    \
    float rm2_ = rb_[tm2];                                                    \
    if (tid == 0) { rm1_ = NPAD; pm_ = NPAD; }                                \
    if (tid <= 1) { rm2_ = NPAD; }                                            \
    if ((TT) == myMel) {   /* rare: mel end on the intermediate step */       \
        alpha_out[b] = (lse2(r, rm1_) + p_) * scale;                          \
    }                                                                         \
    float s_ = lse2(p_, pm_);                                                 \
    float x_ = r + p_;                                                        \
    float y_ = rm1_ + s_;                                                     \
    float z_ = rm2_ + pm_;                                                    \
    r = lse3(x_, y_, z_) + q_;                                                \
    if ((TT) + 1 == myMel) {   /* rare: mel end on the composed step */       \
        alpha_out[b] = r * scale;                                             \
    }                                                                         \
    par ^= 1;                                                                 \
} while (0)

// Kernel 2: serial scan, 4 waves per batch, j = tid (1 text pos per thread).
// lp rows staged CH at a time into double-buffered LDS via global_load_lds
// (per-wave counted vmcnt(4), never drained mid-pipeline). Raw s_barrier per
// pair for the cross-wave neighbor exchange (NOT __syncthreads: that drains
// vmcnt(0) and would serialize staging).
__global__ void __launch_bounds__(256) scan_kernel(
        const float* __restrict__ lpT,          // [B][MEL_T][GSTR], log2-dom
        const int* __restrict__ text_lengths,
        const int* __restrict__ mel_lengths,
        float* __restrict__ alpha_out) {        // [B]
    __shared__ float sbuf[2][CH][GSTR];         // 32 KiB
    __shared__ float rbuf[2][256];              // 2 KiB, parity-dbuf exchange
    const int b = blockIdx.x;
    const int tid = threadIdx.x;
    const int w = tid >> 6;
    const int lane = tid & 63;
    const int j   = tid < TXT_T ? tid : (TXT_T - 1);  // clamp idle threads
    const int jm1 = j > 0 ? j - 1 : 0;
    const int tm1 = tid > 0 ? tid - 1 : 0;
    const int tm2 = tid > 1 ? tid - 2 : 0;

    const int melL1 = mel_lengths[b] - 1;       // in [399, 799]
    const int txtL1 = text_lengths[b] - 1;      // in [99, 199]
    const float scale = LN2 / (float)(melL1 + 1);
    const int myMel = (tid == txtL1) ? melL1 : -1;   // only the genuine lane

    const float* gbase = lpT + (size_t)b * MEL_T * GSTR;
    const int clast = melL1 >> 4;               // in [24, 49]; rows <= 799

    stage16(gbase,             &sbuf[0][0][0], w, lane);
    stage16(gbase + CH * GSTR, &sbuf[1][0][0], w, lane);

    float r = NPAD;
    int par = 0;

    for (int c = 0; c <= clast; ++c) {
        // own chunk-c loads done (chunk c+1 may stay in flight), then sync
        // so every wave's staged rows are visible.
        if (c < clast) { asm volatile("s_waitcnt vmcnt(4)" ::: "memory"); }
        else           { asm volatile("s_waitcnt vmcnt(0)" ::: "memory"); }
        SBAR();

        const float* sb = &sbuf[c & 1][0][0];
        if (c == 0) {
            // state after t=0: a[j=0] = lp(0,0) (stored with eps; remove it)
            float lp00 = sb[0];
            r = (tid == 0) ? (lp00 - EPS2) : NPAD;
            // single step t=1 (melL1 >= 399: no gather possible this chunk)
            {
                float* rb_ = &rbuf[par][0];
                float p_ = sb[GSTR + j];
                rb_[tid] = r;
                WAIT_LGKM0(); SBAR();
                float rm1_ = rb_[tm1];
                if (tid == 0) rm1_ = NPAD;
                r = lse2(r, rm1_) + p_;
                par ^= 1;
            }
            #pragma unroll
            for (int m = 1; m < 8; ++m) {      // pairs (2,3)..(14,15)
                PAIRL(sb, 2 * m, 2 * m);
            }
        } else {
            const int tbase = CH * c;
            #pragma unroll
            for (int m = 0; m < 8; ++m) {      // pairs (0,1)..(14,15) local
                PAIRL(sb, 2 * m, tbase + 2 * m);
            }
        }

        // all waves done reading sbuf[c&1] before DMA overwrites it
        WAIT_LGKM0(); SBAR();
        if (c + 2 <= clast) {
            stage16(gbase + (size_t)(c + 2) * CH * GSTR,
                    &sbuf[c & 1][0][0], w, lane);
        }
    }
}

// Kernel 3: loss = -mean_b alpha[b]
__global__ void finish_kernel(const float* __restrict__ alpha,
                              float* __restrict__ out) {
    float s = 0.f;
    #pragma unroll
    for (int b = 0; b < BB; ++b) s += alpha[b];
    out[0] = -(s / (float)BB);
}

extern "C" void kernel_launch(void* const* d_in, const int* in_sizes, int n_in,
                              void* d_out, int out_size, void* d_ws, size_t ws_size,
                              hipStream_t stream) {
    const float* mu_logvar    = (const float*)d_in[0];
    const float* melspec      = (const float*)d_in[1];
    const int*   text_lengths = (const int*)d_in[2];
    const int*   mel_lengths  = (const int*)d_in[3];
    float* out = (float*)d_out;

    float* alpha = (float*)d_ws;                 // 8 floats
    float* lpT   = (float*)d_ws + 64;            // 256B offset, [B][MEL_T][GSTR]

    lp_kernel<<<BB * TXT_T, 256, 0, stream>>>(mu_logvar, melspec, out + 1, lpT);
    scan_kernel<<<BB, 256, 0, stream>>>(lpT, text_lengths, mel_lengths, alpha);
    finish_kernel<<<1, 1, 0, stream>>>(alpha, out);
}